// Round 1
// baseline (2733.807 us; speedup 1.0000x reference)
//
#include <hip/hip_runtime.h>
#include <stdint.h>

// SquaredExpModel: GP log-likelihood + posterior mean on MI355X (gfx950).
// Pipeline: prep(F->bf16 swizzled tiles) ; r = d_obs - m0*rowsum(F) ;
//   P = sigma^2*exp(-D/(2 l^2)) @ F^T  (fused exp + bf16 MFMA, split-K atomics) ;
//   A = data_cov + F @ P (bf16 MFMA) ; blocked no-pivot LU(A) ;
//   tmp = A^-1 r, logdet = sum log|U_ii| ; out0 = logdet + r.tmp ; out1 = m0 + P@tmp.
// Workspace: ~47.5 MB required.

#define NM 10000
#define ND 552
#define NDP 576
#define NKB 313      // k-blocks of 32 (covers 10016, zero-padded)
#define MT1 79       // M tiles of 128 (covers 10112, guarded)
#define SPLITK 3

typedef __attribute__((ext_vector_type(8))) short bf16x8;
typedef __attribute__((ext_vector_type(4))) float f32x4;

__device__ __forceinline__ unsigned short f2bf(float f){
  unsigned u = __float_as_uint(f);
  u += 0x7fffu + ((u >> 16) & 1u);
  return (unsigned short)(u >> 16);
}
__device__ __forceinline__ unsigned int pk2(unsigned short a, unsigned short b){
  return (unsigned int)a | ((unsigned int)b << 16);
}

// ---- Build Bt: F^T in [kb][n][32k] bf16, 16B-chunk swizzle q' = (q + (n>>1))&3 ----
__global__ void prep_bt(const float* __restrict__ F, unsigned short* __restrict__ Bt){
  int bid = blockIdx.x;
  int kb = bid % NKB, nb = bid / NKB;
  int t = threadIdx.x;
  int nl = t >> 2, q = t & 3;
  int gn = nb * 64 + nl;
  int k0 = kb * 32 + q * 8;
  float v[8];
  if (gn < ND && (k0 + 8) <= NM){
    const float* p = F + (size_t)gn * NM + k0;
    float4 a = *(const float4*)p;
    float4 b = *(const float4*)(p + 4);
    v[0]=a.x; v[1]=a.y; v[2]=a.z; v[3]=a.w; v[4]=b.x; v[5]=b.y; v[6]=b.z; v[7]=b.w;
  } else {
    #pragma unroll
    for (int i = 0; i < 8; ++i) v[i] = 0.f;
  }
  unsigned short u[8];
  #pragma unroll
  for (int i = 0; i < 8; ++i) u[i] = f2bf(v[i]);
  size_t cidx = ((size_t)kb * NDP + gn) * 4 + ((q + (gn >> 1)) & 3);
  uint4 w;
  w.x = pk2(u[0],u[1]); w.y = pk2(u[2],u[3]); w.z = pk2(u[4],u[5]); w.w = pk2(u[6],u[7]);
  *(uint4*)(Bt + cidx * 8) = w;
}

// ---- r = d_obs - m0 * rowsum(F); rows >= ND get 0 ----
__global__ void rvec(const float* __restrict__ F, const float* __restrict__ dobs,
                     const float* __restrict__ m0p, float* __restrict__ r){
  __shared__ float red[256];
  int i = blockIdx.x;
  int t = threadIdx.x;
  float s = 0.f;
  if (i < ND){
    for (int k = t; k < NM; k += 256) s += F[(size_t)i * NM + k];
  }
  red[t] = s;
  __syncthreads();
  if (t < 64){
    float v = red[t] + red[t+64] + red[t+128] + red[t+192];
    #pragma unroll
    for (int off = 32; off; off >>= 1) v += __shfl_down(v, off);
    if (t == 0){
      if (i < ND) r[i] = dobs[i] - m0p[0] * v;
      else        r[i] = 0.f;
    }
  }
}

// ---- GEMM1: P[m][n] += sum_k sigma^2*exp(ce*D[m][k]) * F[n][k]  (bf16 MFMA) ----
// 512 thr = 8 waves in 2(M)x4(N) grid; wave tile 64x144; WG tile 128x576; split-K=3.
__global__ __launch_bounds__(512, 2) void gemm1(
    const float* __restrict__ dist, const unsigned short* __restrict__ Bt,
    float* __restrict__ P, const float* __restrict__ lsp, const float* __restrict__ sgp){
  __shared__ unsigned short Alds[128 * 40];   // padded stride 40 (80B) -> 2-way banks
  __shared__ unsigned short Blds[NDP * 32];   // swizzled chunks, straight copy of Bt block
  int bid = blockIdx.x;
  int mtile = bid % MT1, kc = bid / MT1;
  int kb0 = (kc == 0) ? 0 : (105 + 104 * (kc - 1));
  int kbe = kb0 + ((kc == 0) ? 105 : 104);
  int m0 = mtile * 128;
  float ls = lsp[0], sg = sgp[0];
  float ce = -0.72134752044f / (ls * ls);  // -(log2 e)/(2 l^2)
  float s2 = sg * sg;
  int t = threadIdx.x, lane = t & 63, w = t >> 6;
  int wm = w & 1, wn = w >> 1;
  int c16 = lane & 15, q2 = lane >> 4;
  f32x4 acc[4][9];
  #pragma unroll
  for (int a = 0; a < 4; ++a)
    #pragma unroll
    for (int b = 0; b < 9; ++b) acc[a][b] = (f32x4){0.f, 0.f, 0.f, 0.f};

  int rr = t >> 2, qa = t & 3;
  const int arow = (wm * 64 + c16) * 40 + q2 * 8;

  for (int kb = kb0; kb < kbe; ++kb){
    { // stage A (fused exp -> bf16)
      int gm = m0 + rr;
      int k0 = kb * 32 + qa * 8;
      float v[8];
      if (gm < NM && (k0 + 8) <= NM){
        const float* p = dist + (size_t)gm * NM + k0;
        float4 x = *(const float4*)p;
        float4 y = *(const float4*)(p + 4);
        v[0]=x.x; v[1]=x.y; v[2]=x.z; v[3]=x.w; v[4]=y.x; v[5]=y.y; v[6]=y.z; v[7]=y.w;
        #pragma unroll
        for (int i = 0; i < 8; ++i) v[i] = s2 * exp2f(v[i] * ce);
      } else {
        #pragma unroll
        for (int i = 0; i < 8; ++i) v[i] = 0.f;
      }
      unsigned short u[8];
      #pragma unroll
      for (int i = 0; i < 8; ++i) u[i] = f2bf(v[i]);
      uint4 wv;
      wv.x = pk2(u[0],u[1]); wv.y = pk2(u[2],u[3]); wv.z = pk2(u[4],u[5]); wv.w = pk2(u[6],u[7]);
      *(uint4*)(Alds + rr * 40 + qa * 8) = wv;
    }
    { // stage B (straight copy; 2304 16B chunks)
      const uint4* src = (const uint4*)(Bt + (size_t)kb * NDP * 32);
      uint4* dst = (uint4*)Blds;
      for (int i = t; i < 2304; i += 512) dst[i] = src[i];
    }
    __syncthreads();
    bf16x8 af[4];
    #pragma unroll
    for (int mt = 0; mt < 4; ++mt)
      af[mt] = *(const bf16x8*)&Alds[arow + mt * 16 * 40];
    #pragma unroll
    for (int nt = 0; nt < 9; ++nt){
      int n = wn * 144 + nt * 16 + c16;
      int cidx = n * 4 + ((q2 + (n >> 1)) & 3);
      bf16x8 bf = *(const bf16x8*)&Blds[cidx * 8];
      #pragma unroll
      for (int mt = 0; mt < 4; ++mt)
        acc[mt][nt] = __builtin_amdgcn_mfma_f32_16x16x32_bf16(af[mt], bf, acc[mt][nt], 0, 0, 0);
    }
    __syncthreads();
  }
  // epilogue: split-K accumulate
  #pragma unroll
  for (int mt = 0; mt < 4; ++mt)
    #pragma unroll
    for (int nt = 0; nt < 9; ++nt)
      #pragma unroll
      for (int e = 0; e < 4; ++e){
        int gm = m0 + wm * 64 + mt * 16 + q2 * 4 + e;
        int gn = wn * 144 + nt * 16 + c16;
        if (gm < NM) atomicAdd(&P[(size_t)gm * NDP + gn], acc[mt][nt][e]);
      }
}

// ---- Convert P (fp32 [k][n]) -> Pb bf16 swizzled tiles [kb][n][32k] ----
__global__ void conv_p(const float* __restrict__ P, unsigned short* __restrict__ Pb){
  int bid = blockIdx.x;
  int kb = bid % NKB, nb = bid / NKB;
  int t = threadIdx.x;
  int nl = t & 63, q = t >> 6;
  int gn = nb * 64 + nl;
  int k0 = kb * 32 + q * 8;
  unsigned short u[8];
  #pragma unroll
  for (int j = 0; j < 8; ++j){
    int k = k0 + j;
    float v = (k < NM) ? P[(size_t)k * NDP + gn] : 0.f;
    u[j] = f2bf(v);
  }
  size_t cidx = ((size_t)kb * NDP + gn) * 4 + ((q + (gn >> 1)) & 3);
  uint4 w;
  w.x = pk2(u[0],u[1]); w.y = pk2(u[2],u[3]); w.z = pk2(u[4],u[5]); w.w = pk2(u[6],u[7]);
  *(uint4*)(Pb + cidx * 8) = w;
}

// ---- A init: padded data_cov with identity pad block ----
__global__ void a_init(const float* __restrict__ dcov, float* __restrict__ A){
  int idx = blockIdx.x * 256 + threadIdx.x;
  if (idx >= NDP * NDP) return;
  int i = idx / NDP, j = idx % NDP;
  float v;
  if (i < ND && j < ND) v = dcov[i * ND + j];
  else v = (i == j) ? 1.f : 0.f;
  A[idx] = v;
}

// ---- GEMM2: A += F @ P (bf16 MFMA, 64x64 tiles, split-K=3, fp32 atomics) ----
__global__ __launch_bounds__(256) void gemm2(
    const unsigned short* __restrict__ Bt, const unsigned short* __restrict__ Pb,
    float* __restrict__ A){
  __shared__ unsigned short Fa[64 * 32];
  __shared__ unsigned short Pl[64 * 32];
  int bid = blockIdx.x;
  int tile = bid % 81, kc = bid / 81;
  int ti = tile / 9, tj = tile % 9;
  int i0 = ti * 64, j0 = tj * 64;
  int kb0 = (kc == 0) ? 0 : (105 + 104 * (kc - 1));
  int kbe = kb0 + ((kc == 0) ? 105 : 104);
  int t = threadIdx.x, lane = t & 63, w = t >> 6;
  int wm = w & 1, wn = w >> 1;
  int c16 = lane & 15, q2 = lane >> 4;
  f32x4 acc[2][2];
  #pragma unroll
  for (int a = 0; a < 2; ++a)
    #pragma unroll
    for (int b = 0; b < 2; ++b) acc[a][b] = (f32x4){0.f, 0.f, 0.f, 0.f};
  for (int kb = kb0; kb < kbe; ++kb){
    ((uint4*)Fa)[t] = ((const uint4*)Bt)[((size_t)kb * NDP + i0) * 4 + t];
    ((uint4*)Pl)[t] = ((const uint4*)Pb)[((size_t)kb * NDP + j0) * 4 + t];
    __syncthreads();
    bf16x8 af[2], bf[2];
    #pragma unroll
    for (int mt = 0; mt < 2; ++mt){
      int il = wm * 32 + mt * 16 + c16;
      af[mt] = *(const bf16x8*)&Fa[(il * 4 + ((q2 + (il >> 1)) & 3)) * 8];
    }
    #pragma unroll
    for (int nt = 0; nt < 2; ++nt){
      int jl = wn * 32 + nt * 16 + c16;
      bf[nt] = *(const bf16x8*)&Pl[(jl * 4 + ((q2 + (jl >> 1)) & 3)) * 8];
    }
    #pragma unroll
    for (int mt = 0; mt < 2; ++mt)
      #pragma unroll
      for (int nt = 0; nt < 2; ++nt)
        acc[mt][nt] = __builtin_amdgcn_mfma_f32_16x16x32_bf16(af[mt], bf[nt], acc[mt][nt], 0, 0, 0);
    __syncthreads();
  }
  #pragma unroll
  for (int mt = 0; mt < 2; ++mt)
    #pragma unroll
    for (int nt = 0; nt < 2; ++nt)
      #pragma unroll
      for (int e = 0; e < 4; ++e){
        int gi = i0 + wm * 32 + mt * 16 + q2 * 4 + e;
        int gj = j0 + wn * 32 + nt * 16 + c16;
        atomicAdd(&A[(size_t)gi * NDP + gj], acc[mt][nt][e]);
      }
}

// ---- LU (no pivoting), blocked nb=64 ----
__global__ void lu_diag(float* __restrict__ A, int k0){
  __shared__ float lds[64 * 65];
  int l = threadIdx.x;  // 64 threads = 1 wave
  for (int idx = l; idx < 4096; idx += 64){
    int i = idx >> 6, c = idx & 63;
    lds[i * 65 + c] = A[(size_t)(k0 + i) * NDP + k0 + c];
  }
  __syncthreads();
  float r[64];
  #pragma unroll
  for (int c = 0; c < 64; ++c) r[c] = lds[l * 65 + c];
  #pragma unroll
  for (int j = 0; j < 64; ++j){
    float piv = __shfl(r[j], j);
    float lij = r[j] / piv;
    float m = (l > j) ? 1.f : 0.f;
    float mlij = m * lij;
    #pragma unroll
    for (int c = j + 1; c < 64; ++c){
      float rjc = __shfl(r[c], j);
      r[c] -= mlij * rjc;
    }
    if (l > j) r[j] = lij;
  }
  #pragma unroll
  for (int c = 0; c < 64; ++c) lds[l * 65 + c] = r[c];
  __syncthreads();
  for (int idx = l; idx < 4096; idx += 64){
    int i = idx >> 6, c = idx & 63;
    A[(size_t)(k0 + i) * NDP + k0 + c] = lds[i * 65 + c];
  }
}

__global__ void lu_trsm(float* __restrict__ A, int k0){
  __shared__ float Dg[64 * 65];
  __shared__ float Cc[64 * 65];
  int l = threadIdx.x;  // 64
  int nch = (NDP - k0 - 64) >> 6;
  int bid = blockIdx.x;
  bool isU = bid < nch;
  int ch = isU ? bid : bid - nch;
  int c0 = k0 + 64 + ch * 64;
  for (int idx = l; idx < 4096; idx += 64){
    int i = idx >> 6, c = idx & 63;
    Dg[i * 65 + c] = A[(size_t)(k0 + i) * NDP + k0 + c];
  }
  if (isU){
    float y[64];
    #pragma unroll
    for (int i = 0; i < 64; ++i) y[i] = A[(size_t)(k0 + i) * NDP + c0 + l];
    __syncthreads();
    #pragma unroll
    for (int i = 0; i < 64; ++i){
      #pragma unroll
      for (int ii = i + 1; ii < 64; ++ii)
        y[ii] -= Dg[ii * 65 + i] * y[i];
    }
    #pragma unroll
    for (int i = 0; i < 64; ++i) A[(size_t)(k0 + i) * NDP + c0 + l] = y[i];
  } else {
    for (int idx = l; idx < 4096; idx += 64){
      int i = idx >> 6, c = idx & 63;
      Cc[i * 65 + c] = A[(size_t)(c0 + i) * NDP + k0 + c];
    }
    __syncthreads();
    float x[64];
    #pragma unroll
    for (int j = 0; j < 64; ++j) x[j] = Cc[l * 65 + j];
    #pragma unroll
    for (int j = 0; j < 64; ++j){
      x[j] /= Dg[j * 65 + j];
      #pragma unroll
      for (int jj = j + 1; jj < 64; ++jj)
        x[jj] -= x[j] * Dg[j * 65 + jj];
    }
    #pragma unroll
    for (int j = 0; j < 64; ++j) Cc[l * 65 + j] = x[j];
    __syncthreads();
    for (int idx = l; idx < 4096; idx += 64){
      int i = idx >> 6, c = idx & 63;
      A[(size_t)(c0 + i) * NDP + k0 + c] = Cc[i * 65 + c];
    }
  }
}

__global__ __launch_bounds__(256) void lu_gemmk(float* __restrict__ A, int k0){
  __shared__ float Lt[32 * 65];
  __shared__ float Ut[64 * 33];
  int n2 = NDP - k0 - 64;
  int nb = n2 >> 5;
  int bx = blockIdx.x % nb, by = blockIdx.x / nb;
  int r0 = k0 + 64 + bx * 32, c0 = k0 + 64 + by * 32;
  int t = threadIdx.x;
  for (int idx = t; idx < 2048; idx += 256){
    int i = idx >> 6, kk = idx & 63;
    Lt[i * 65 + kk] = A[(size_t)(r0 + i) * NDP + k0 + kk];
  }
  for (int idx = t; idx < 2048; idx += 256){
    int kk = idx >> 5, j = idx & 31;
    Ut[kk * 33 + j] = A[(size_t)(k0 + kk) * NDP + c0 + j];
  }
  __syncthreads();
  int i = t >> 3, j4 = (t & 7) * 4;
  float acc[4] = {0.f, 0.f, 0.f, 0.f};
  for (int kk = 0; kk < 64; ++kk){
    float lv = Lt[i * 65 + kk];
    #pragma unroll
    for (int u = 0; u < 4; ++u) acc[u] += lv * Ut[kk * 33 + j4 + u];
  }
  float* dst = &A[(size_t)(r0 + i) * NDP + c0 + j4];
  #pragma unroll
  for (int u = 0; u < 4; ++u) dst[u] -= acc[u];
}

// ---- Solve L U tmp = r ; logdet ; out0 = logdet + r.tmp ----
__device__ __forceinline__ void stage_blk(const float* __restrict__ A, float* __restrict__ B,
                                          int l, int br, int bc){
  for (int idx = l; idx < 4096; idx += 64){
    int i = idx >> 6, c = idx & 63;
    B[i * 65 + c] = A[(size_t)(br * 64 + i) * NDP + bc * 64 + c];
  }
}
__global__ void solve_ll(const float* __restrict__ A, const float* __restrict__ r,
                         float* __restrict__ tmp, float* __restrict__ out0){
  __shared__ float B[64 * 65];
  int l = threadIdx.x;  // 64
  float y[9];
  #pragma unroll
  for (int b = 0; b < 9; ++b) y[b] = r[b * 64 + l];
  // forward: unit-lower
  #pragma unroll
  for (int b = 0; b < 9; ++b){
    #pragma unroll
    for (int pb = 0; pb < b; ++pb){
      stage_blk(A, B, l, b, pb);
      __syncthreads();
      for (int j = 0; j < 64; ++j){
        float yj = __shfl(y[pb], j);
        y[b] -= B[l * 65 + j] * yj;
      }
      __syncthreads();
    }
    stage_blk(A, B, l, b, b);
    __syncthreads();
    for (int j = 0; j < 64; ++j){
      float yj = __shfl(y[b], j);
      if (l > j) y[b] -= B[l * 65 + j] * yj;
    }
    __syncthreads();
  }
  // backward: upper
  #pragma unroll
  for (int b = 8; b >= 0; --b){
    #pragma unroll
    for (int pb = b + 1; pb < 9; ++pb){
      stage_blk(A, B, l, b, pb);
      __syncthreads();
      for (int j = 0; j < 64; ++j){
        float yj = __shfl(y[pb], j);
        y[b] -= B[l * 65 + j] * yj;
      }
      __syncthreads();
    }
    stage_blk(A, B, l, b, b);
    __syncthreads();
    for (int j = 63; j >= 0; --j){
      float yj = __shfl(y[b], j);
      yj = yj / B[j * 65 + j];
      if (l == j) y[b] = yj;
      if (l < j)  y[b] -= B[l * 65 + j] * yj;
    }
    __syncthreads();
  }
  float ld = 0.f, dt = 0.f;
  #pragma unroll
  for (int b = 0; b < 9; ++b){
    int i = b * 64 + l;
    ld += logf(fabsf(A[(size_t)i * NDP + i]));
    dt += r[i] * y[b];
    tmp[i] = y[b];
  }
  #pragma unroll
  for (int off = 32; off; off >>= 1){
    ld += __shfl_down(ld, off);
    dt += __shfl_down(dt, off);
  }
  if (l == 0) out0[0] = ld + dt;
}

// ---- m_posterior = m0 + P @ tmp ----
__global__ void mpost(const float* __restrict__ P, const float* __restrict__ tmp,
                      const float* __restrict__ m0p, float* __restrict__ out1){
  int w = threadIdx.x >> 6, l = threadIdx.x & 63;
  int m = blockIdx.x * 4 + w;
  if (m >= NM) return;
  float s = 0.f;
  #pragma unroll
  for (int i = 0; i < 9; ++i){
    int n = i * 64 + l;
    s += P[(size_t)m * NDP + n] * tmp[n];
  }
  #pragma unroll
  for (int off = 32; off; off >>= 1) s += __shfl_down(s, off);
  if (l == 0) out1[m] = m0p[0] + s;
}

extern "C" void kernel_launch(void* const* d_in, const int* in_sizes, int n_in,
                              void* d_out, int out_size, void* d_ws, size_t ws_size,
                              hipStream_t stream){
  const float* dist = (const float*)d_in[0];
  const float* F    = (const float*)d_in[1];
  const float* dobs = (const float*)d_in[2];
  const float* dcov = (const float*)d_in[3];
  const float* m0p  = (const float*)d_in[4];
  const float* lsp  = (const float*)d_in[5];
  const float* sgp  = (const float*)d_in[6];
  float* out = (float*)d_out;
  char* ws = (char*)d_ws;

  unsigned short* Bt = (unsigned short*)(ws + 0);          // 11,538,432 B
  float*          P  = (float*)(ws + 11538432);            // 23,040,000 B
  unsigned short* Pb = (unsigned short*)(ws + 34578432);   // 11,538,432 B
  float*          A  = (float*)(ws + 46116864);            //  1,327,104 B
  float*          r  = (float*)(ws + 47443968);            //      2,304 B
  float*          tp = (float*)(ws + 47446272);            //      2,304 B

  hipMemsetAsync(P, 0, (size_t)NM * NDP * sizeof(float), stream);
  prep_bt<<<NKB * 9, 256, 0, stream>>>(F, Bt);
  rvec<<<NDP, 256, 0, stream>>>(F, dobs, m0p, r);
  gemm1<<<MT1 * SPLITK, 512, 0, stream>>>(dist, Bt, P, lsp, sgp);
  conv_p<<<NKB * 9, 256, 0, stream>>>(P, Pb);
  a_init<<<(NDP * NDP) / 256, 256, 0, stream>>>(dcov, A);
  gemm2<<<81 * 3, 256, 0, stream>>>(Bt, Pb, A);
  for (int k = 0; k < 9; ++k){
    lu_diag<<<1, 64, 0, stream>>>(A, k * 64);
    if (k < 8){
      int nch = 8 - k;
      lu_trsm<<<2 * nch, 64, 0, stream>>>(A, k * 64);
      int nb = (NDP - k * 64 - 64) >> 5;
      lu_gemmk<<<nb * nb, 256, 0, stream>>>(A, k * 64);
    }
  }
  solve_ll<<<1, 64, 0, stream>>>(A, r, tp, out);
  mpost<<<2500, 256, 0, stream>>>(P, tp, m0p, out + 1);
}

// Round 2
// 1752.262 us; speedup vs baseline: 1.5602x; 1.5602x over previous
//
#include <hip/hip_runtime.h>
#include <stdint.h>

// SquaredExpModel: GP log-likelihood + posterior mean on MI355X (gfx950).
// R2: parallelized triangular solve (576-thr, register rows) + cooperative
// staging in lu_diag/lu_trsm (R1's single-wave scalar staging was 1.45 ms).

#define NM 10000
#define ND 552
#define NDP 576
#define NKB 313      // k-blocks of 32 (covers 10016, zero-padded)
#define MT1 79       // M tiles of 128 (covers 10112, guarded)
#define SPLITK 3

typedef __attribute__((ext_vector_type(8))) short bf16x8;
typedef __attribute__((ext_vector_type(4))) float f32x4;

__device__ __forceinline__ unsigned short f2bf(float f){
  unsigned u = __float_as_uint(f);
  u += 0x7fffu + ((u >> 16) & 1u);
  return (unsigned short)(u >> 16);
}
__device__ __forceinline__ unsigned int pk2(unsigned short a, unsigned short b){
  return (unsigned int)a | ((unsigned int)b << 16);
}

// ---- Build Bt: F^T in [kb][n][32k] bf16, 16B-chunk swizzle q' = (q + (n>>1))&3 ----
__global__ void prep_bt(const float* __restrict__ F, unsigned short* __restrict__ Bt){
  int bid = blockIdx.x;
  int kb = bid % NKB, nb = bid / NKB;
  int t = threadIdx.x;
  int nl = t >> 2, q = t & 3;
  int gn = nb * 64 + nl;
  int k0 = kb * 32 + q * 8;
  float v[8];
  if (gn < ND && (k0 + 8) <= NM){
    const float* p = F + (size_t)gn * NM + k0;
    float4 a = *(const float4*)p;
    float4 b = *(const float4*)(p + 4);
    v[0]=a.x; v[1]=a.y; v[2]=a.z; v[3]=a.w; v[4]=b.x; v[5]=b.y; v[6]=b.z; v[7]=b.w;
  } else {
    #pragma unroll
    for (int i = 0; i < 8; ++i) v[i] = 0.f;
  }
  unsigned short u[8];
  #pragma unroll
  for (int i = 0; i < 8; ++i) u[i] = f2bf(v[i]);
  size_t cidx = ((size_t)kb * NDP + gn) * 4 + ((q + (gn >> 1)) & 3);
  uint4 w;
  w.x = pk2(u[0],u[1]); w.y = pk2(u[2],u[3]); w.z = pk2(u[4],u[5]); w.w = pk2(u[6],u[7]);
  *(uint4*)(Bt + cidx * 8) = w;
}

// ---- r = d_obs - m0 * rowsum(F); rows >= ND get 0 ----
__global__ void rvec(const float* __restrict__ F, const float* __restrict__ dobs,
                     const float* __restrict__ m0p, float* __restrict__ r){
  __shared__ float red[256];
  int i = blockIdx.x;
  int t = threadIdx.x;
  float s = 0.f;
  if (i < ND){
    for (int k = t; k < NM; k += 256) s += F[(size_t)i * NM + k];
  }
  red[t] = s;
  __syncthreads();
  if (t < 64){
    float v = red[t] + red[t+64] + red[t+128] + red[t+192];
    #pragma unroll
    for (int off = 32; off; off >>= 1) v += __shfl_down(v, off);
    if (t == 0){
      if (i < ND) r[i] = dobs[i] - m0p[0] * v;
      else        r[i] = 0.f;
    }
  }
}

// ---- GEMM1: P[m][n] += sum_k sigma^2*exp(ce*D[m][k]) * F[n][k]  (bf16 MFMA) ----
__global__ __launch_bounds__(512, 2) void gemm1(
    const float* __restrict__ dist, const unsigned short* __restrict__ Bt,
    float* __restrict__ P, const float* __restrict__ lsp, const float* __restrict__ sgp){
  __shared__ unsigned short Alds[128 * 40];
  __shared__ unsigned short Blds[NDP * 32];
  int bid = blockIdx.x;
  int mtile = bid % MT1, kc = bid / MT1;
  int kb0 = (kc == 0) ? 0 : (105 + 104 * (kc - 1));
  int kbe = kb0 + ((kc == 0) ? 105 : 104);
  int m0 = mtile * 128;
  float ls = lsp[0], sg = sgp[0];
  float ce = -0.72134752044f / (ls * ls);  // -(log2 e)/(2 l^2)
  float s2 = sg * sg;
  int t = threadIdx.x, lane = t & 63, w = t >> 6;
  int wm = w & 1, wn = w >> 1;
  int c16 = lane & 15, q2 = lane >> 4;
  f32x4 acc[4][9];
  #pragma unroll
  for (int a = 0; a < 4; ++a)
    #pragma unroll
    for (int b = 0; b < 9; ++b) acc[a][b] = (f32x4){0.f, 0.f, 0.f, 0.f};

  int rr = t >> 2, qa = t & 3;
  const int arow = (wm * 64 + c16) * 40 + q2 * 8;

  for (int kb = kb0; kb < kbe; ++kb){
    { // stage A (fused exp -> bf16)
      int gm = m0 + rr;
      int k0 = kb * 32 + qa * 8;
      float v[8];
      if (gm < NM && (k0 + 8) <= NM){
        const float* p = dist + (size_t)gm * NM + k0;
        float4 x = *(const float4*)p;
        float4 y = *(const float4*)(p + 4);
        v[0]=x.x; v[1]=x.y; v[2]=x.z; v[3]=x.w; v[4]=y.x; v[5]=y.y; v[6]=y.z; v[7]=y.w;
        #pragma unroll
        for (int i = 0; i < 8; ++i) v[i] = s2 * exp2f(v[i] * ce);
      } else {
        #pragma unroll
        for (int i = 0; i < 8; ++i) v[i] = 0.f;
      }
      unsigned short u[8];
      #pragma unroll
      for (int i = 0; i < 8; ++i) u[i] = f2bf(v[i]);
      uint4 wv;
      wv.x = pk2(u[0],u[1]); wv.y = pk2(u[2],u[3]); wv.z = pk2(u[4],u[5]); wv.w = pk2(u[6],u[7]);
      *(uint4*)(Alds + rr * 40 + qa * 8) = wv;
    }
    { // stage B
      const uint4* src = (const uint4*)(Bt + (size_t)kb * NDP * 32);
      uint4* dst = (uint4*)Blds;
      for (int i = t; i < 2304; i += 512) dst[i] = src[i];
    }
    __syncthreads();
    bf16x8 af[4];
    #pragma unroll
    for (int mt = 0; mt < 4; ++mt)
      af[mt] = *(const bf16x8*)&Alds[arow + mt * 16 * 40];
    #pragma unroll
    for (int nt = 0; nt < 9; ++nt){
      int n = wn * 144 + nt * 16 + c16;
      int cidx = n * 4 + ((q2 + (n >> 1)) & 3);
      bf16x8 bf = *(const bf16x8*)&Blds[cidx * 8];
      #pragma unroll
      for (int mt = 0; mt < 4; ++mt)
        acc[mt][nt] = __builtin_amdgcn_mfma_f32_16x16x32_bf16(af[mt], bf, acc[mt][nt], 0, 0, 0);
    }
    __syncthreads();
  }
  #pragma unroll
  for (int mt = 0; mt < 4; ++mt)
    #pragma unroll
    for (int nt = 0; nt < 9; ++nt)
      #pragma unroll
      for (int e = 0; e < 4; ++e){
        int gm = m0 + wm * 64 + mt * 16 + q2 * 4 + e;
        int gn = wn * 144 + nt * 16 + c16;
        if (gm < NM) atomicAdd(&P[(size_t)gm * NDP + gn], acc[mt][nt][e]);
      }
}

// ---- Convert P (fp32 [k][n]) -> Pb bf16 swizzled tiles [kb][n][32k] ----
__global__ void conv_p(const float* __restrict__ P, unsigned short* __restrict__ Pb){
  int bid = blockIdx.x;
  int kb = bid % NKB, nb = bid / NKB;
  int t = threadIdx.x;
  int nl = t & 63, q = t >> 6;
  int gn = nb * 64 + nl;
  int k0 = kb * 32 + q * 8;
  unsigned short u[8];
  #pragma unroll
  for (int j = 0; j < 8; ++j){
    int k = k0 + j;
    float v = (k < NM) ? P[(size_t)k * NDP + gn] : 0.f;
    u[j] = f2bf(v);
  }
  size_t cidx = ((size_t)kb * NDP + gn) * 4 + ((q + (gn >> 1)) & 3);
  uint4 w;
  w.x = pk2(u[0],u[1]); w.y = pk2(u[2],u[3]); w.z = pk2(u[4],u[5]); w.w = pk2(u[6],u[7]);
  *(uint4*)(Pb + cidx * 8) = w;
}

// ---- A init ----
__global__ void a_init(const float* __restrict__ dcov, float* __restrict__ A){
  int idx = blockIdx.x * 256 + threadIdx.x;
  if (idx >= NDP * NDP) return;
  int i = idx / NDP, j = idx % NDP;
  float v;
  if (i < ND && j < ND) v = dcov[i * ND + j];
  else v = (i == j) ? 1.f : 0.f;
  A[idx] = v;
}

// ---- GEMM2: A += F @ P ----
__global__ __launch_bounds__(256) void gemm2(
    const unsigned short* __restrict__ Bt, const unsigned short* __restrict__ Pb,
    float* __restrict__ A){
  __shared__ unsigned short Fa[64 * 32];
  __shared__ unsigned short Pl[64 * 32];
  int bid = blockIdx.x;
  int tile = bid % 81, kc = bid / 81;
  int ti = tile / 9, tj = tile % 9;
  int i0 = ti * 64, j0 = tj * 64;
  int kb0 = (kc == 0) ? 0 : (105 + 104 * (kc - 1));
  int kbe = kb0 + ((kc == 0) ? 105 : 104);
  int t = threadIdx.x, lane = t & 63, w = t >> 6;
  int wm = w & 1, wn = w >> 1;
  int c16 = lane & 15, q2 = lane >> 4;
  f32x4 acc[2][2];
  #pragma unroll
  for (int a = 0; a < 2; ++a)
    #pragma unroll
    for (int b = 0; b < 2; ++b) acc[a][b] = (f32x4){0.f, 0.f, 0.f, 0.f};
  for (int kb = kb0; kb < kbe; ++kb){
    ((uint4*)Fa)[t] = ((const uint4*)Bt)[((size_t)kb * NDP + i0) * 4 + t];
    ((uint4*)Pl)[t] = ((const uint4*)Pb)[((size_t)kb * NDP + j0) * 4 + t];
    __syncthreads();
    bf16x8 af[2], bf[2];
    #pragma unroll
    for (int mt = 0; mt < 2; ++mt){
      int il = wm * 32 + mt * 16 + c16;
      af[mt] = *(const bf16x8*)&Fa[(il * 4 + ((q2 + (il >> 1)) & 3)) * 8];
    }
    #pragma unroll
    for (int nt = 0; nt < 2; ++nt){
      int jl = wn * 32 + nt * 16 + c16;
      bf[nt] = *(const bf16x8*)&Pl[(jl * 4 + ((q2 + (jl >> 1)) & 3)) * 8];
    }
    #pragma unroll
    for (int mt = 0; mt < 2; ++mt)
      #pragma unroll
      for (int nt = 0; nt < 2; ++nt)
        acc[mt][nt] = __builtin_amdgcn_mfma_f32_16x16x32_bf16(af[mt], bf[nt], acc[mt][nt], 0, 0, 0);
    __syncthreads();
  }
  #pragma unroll
  for (int mt = 0; mt < 2; ++mt)
    #pragma unroll
    for (int nt = 0; nt < 2; ++nt)
      #pragma unroll
      for (int e = 0; e < 4; ++e){
        int gi = i0 + wm * 32 + mt * 16 + q2 * 4 + e;
        int gj = j0 + wn * 32 + nt * 16 + c16;
        atomicAdd(&A[(size_t)gi * NDP + gj], acc[mt][nt][e]);
      }
}

// ---- LU (no pivoting), blocked nb=64; cooperative float4 staging ----
__global__ __launch_bounds__(256) void lu_diag(float* __restrict__ A, int k0){
  __shared__ float lds[64 * 65];
  int t = threadIdx.x;
  for (int fid = t; fid < 1024; fid += 256){
    int row = fid >> 4, c4 = (fid & 15) << 2;
    float4 v = *(const float4*)&A[(size_t)(k0 + row) * NDP + k0 + c4];
    lds[row * 65 + c4 + 0] = v.x; lds[row * 65 + c4 + 1] = v.y;
    lds[row * 65 + c4 + 2] = v.z; lds[row * 65 + c4 + 3] = v.w;
  }
  __syncthreads();
  if (t < 64){
    int l = t;
    float r[64];
    #pragma unroll
    for (int c = 0; c < 64; ++c) r[c] = lds[l * 65 + c];
    #pragma unroll
    for (int j = 0; j < 64; ++j){
      float piv = __shfl(r[j], j);
      float lij = r[j] / piv;
      float m = (l > j) ? 1.f : 0.f;
      float mlij = m * lij;
      #pragma unroll
      for (int c = j + 1; c < 64; ++c){
        float rjc = __shfl(r[c], j);
        r[c] -= mlij * rjc;
      }
      if (l > j) r[j] = lij;
    }
    #pragma unroll
    for (int c = 0; c < 64; ++c) lds[l * 65 + c] = r[c];
  }
  __syncthreads();
  for (int fid = t; fid < 1024; fid += 256){
    int row = fid >> 4, c4 = (fid & 15) << 2;
    float4 v;
    v.x = lds[row * 65 + c4 + 0]; v.y = lds[row * 65 + c4 + 1];
    v.z = lds[row * 65 + c4 + 2]; v.w = lds[row * 65 + c4 + 3];
    *(float4*)&A[(size_t)(k0 + row) * NDP + k0 + c4] = v;
  }
}

__global__ __launch_bounds__(256) void lu_trsm(float* __restrict__ A, int k0){
  __shared__ float Dg[64 * 65];
  __shared__ float Tg[64 * 65];
  int t = threadIdx.x;
  int nch = (NDP - k0 - 64) >> 6;
  int bid = blockIdx.x;
  bool isU = bid < nch;
  int ch = isU ? bid : bid - nch;
  int c0 = k0 + 64 + ch * 64;
  int rbase = isU ? k0 : c0;
  int cbase = isU ? c0 : k0;
  for (int fid = t; fid < 1024; fid += 256){
    int row = fid >> 4, c4 = (fid & 15) << 2;
    float4 v = *(const float4*)&A[(size_t)(k0 + row) * NDP + k0 + c4];
    Dg[row * 65 + c4 + 0] = v.x; Dg[row * 65 + c4 + 1] = v.y;
    Dg[row * 65 + c4 + 2] = v.z; Dg[row * 65 + c4 + 3] = v.w;
  }
  for (int fid = t; fid < 1024; fid += 256){
    int row = fid >> 4, c4 = (fid & 15) << 2;
    float4 v = *(const float4*)&A[(size_t)(rbase + row) * NDP + cbase + c4];
    Tg[row * 65 + c4 + 0] = v.x; Tg[row * 65 + c4 + 1] = v.y;
    Tg[row * 65 + c4 + 2] = v.z; Tg[row * 65 + c4 + 3] = v.w;
  }
  __syncthreads();
  if (t < 64){
    if (isU){
      // solve L X = T; lane owns column t
      float x[64];
      #pragma unroll
      for (int i = 0; i < 64; ++i) x[i] = Tg[i * 65 + t];
      #pragma unroll
      for (int i = 0; i < 64; ++i){
        #pragma unroll
        for (int ii = i + 1; ii < 64; ++ii)
          x[ii] -= Dg[ii * 65 + i] * x[i];
      }
      #pragma unroll
      for (int i = 0; i < 64; ++i) Tg[i * 65 + t] = x[i];
    } else {
      // solve X U = T; lane owns row t
      float x[64];
      #pragma unroll
      for (int j = 0; j < 64; ++j) x[j] = Tg[t * 65 + j];
      #pragma unroll
      for (int j = 0; j < 64; ++j){
        x[j] /= Dg[j * 65 + j];
        #pragma unroll
        for (int jj = j + 1; jj < 64; ++jj)
          x[jj] -= x[j] * Dg[j * 65 + jj];
      }
      #pragma unroll
      for (int j = 0; j < 64; ++j) Tg[t * 65 + j] = x[j];
    }
  }
  __syncthreads();
  for (int fid = t; fid < 1024; fid += 256){
    int row = fid >> 4, c4 = (fid & 15) << 2;
    float4 v;
    v.x = Tg[row * 65 + c4 + 0]; v.y = Tg[row * 65 + c4 + 1];
    v.z = Tg[row * 65 + c4 + 2]; v.w = Tg[row * 65 + c4 + 3];
    *(float4*)&A[(size_t)(rbase + row) * NDP + cbase + c4] = v;
  }
}

__global__ __launch_bounds__(256) void lu_gemmk(float* __restrict__ A, int k0){
  __shared__ float Lt[32 * 65];
  __shared__ float Ut[64 * 33];
  int n2 = NDP - k0 - 64;
  int nb = n2 >> 5;
  int bx = blockIdx.x % nb, by = blockIdx.x / nb;
  int r0 = k0 + 64 + bx * 32, c0 = k0 + 64 + by * 32;
  int t = threadIdx.x;
  for (int idx = t; idx < 2048; idx += 256){
    int i = idx >> 6, kk = idx & 63;
    Lt[i * 65 + kk] = A[(size_t)(r0 + i) * NDP + k0 + kk];
  }
  for (int idx = t; idx < 2048; idx += 256){
    int kk = idx >> 5, j = idx & 31;
    Ut[kk * 33 + j] = A[(size_t)(k0 + kk) * NDP + c0 + j];
  }
  __syncthreads();
  int i = t >> 3, j4 = (t & 7) * 4;
  float acc[4] = {0.f, 0.f, 0.f, 0.f};
  for (int kk = 0; kk < 64; ++kk){
    float lv = Lt[i * 65 + kk];
    #pragma unroll
    for (int u = 0; u < 4; ++u) acc[u] += lv * Ut[kk * 33 + j4 + u];
  }
  float* dst = &A[(size_t)(r0 + i) * NDP + c0 + j4];
  #pragma unroll
  for (int u = 0; u < 4; ++u) dst[u] -= acc[u];
}

// ---- Parallel solve: 576 threads, thread i owns row i ----
// Forward: unit-lower L; Backward: upper U. Diag block = exactly one wave.
__global__ __launch_bounds__(576) void solve_ll(
    const float* __restrict__ A, const float* __restrict__ r,
    float* __restrict__ tmp, float* __restrict__ out0){
  __shared__ float ys[NDP];
  __shared__ float red[16];
  int t = threadIdx.x;
  int w = t >> 6, l = t & 63;
  int i = t;
  float y = r[i];
  float rsave = y;
  float ldpart = 0.f;
  float row[64];

  // ---- forward: L y' = r ----
  for (int jb = 0; jb < 9; ++jb){
    if (w >= jb){
      const float4* ap = (const float4*)(A + (size_t)i * NDP + jb * 64);
      #pragma unroll
      for (int q = 0; q < 16; ++q) ((float4*)row)[q] = ap[q];
    }
    if (w == jb){
      #pragma unroll
      for (int j = 0; j < 64; ++j){
        float yj = __shfl(y, j);
        if (l > j) y -= row[j] * yj;
      }
      ys[i] = y;
    }
    __syncthreads();
    if (w > jb){
      #pragma unroll
      for (int j = 0; j < 64; ++j) y -= row[j] * ys[jb * 64 + j];
    }
  }
  __syncthreads();

  // ---- backward: U y = y' ----
  for (int jb = 8; jb >= 0; --jb){
    if (w <= jb){
      const float4* ap = (const float4*)(A + (size_t)i * NDP + jb * 64);
      #pragma unroll
      for (int q = 0; q < 16; ++q) ((float4*)row)[q] = ap[q];
    }
    if (w == jb){
      float dv = A[(size_t)i * NDP + i];   // own diagonal
      float dinv = 1.f / dv;
      ldpart = logf(fabsf(dv));
      #pragma unroll
      for (int j = 63; j >= 0; --j){
        float yj = __shfl(y, j) * __shfl(dinv, j);
        if (l == j) y = yj;
        if (l < j)  y -= row[j] * yj;
      }
      ys[i] = y;
    }
    __syncthreads();
    if (w < jb){
      #pragma unroll
      for (int j = 0; j < 64; ++j) y -= row[j] * ys[jb * 64 + j];
    }
  }

  tmp[i] = y;
  // out0 = sum(log|U_ii|) + r . y
  float contrib = ldpart + rsave * y;
  #pragma unroll
  for (int off = 32; off; off >>= 1) contrib += __shfl_down(contrib, off);
  if (l == 0) red[w] = contrib;
  __syncthreads();
  if (t == 0){
    float s = 0.f;
    #pragma unroll
    for (int k = 0; k < 9; ++k) s += red[k];
    out0[0] = s;
  }
}

// ---- m_posterior = m0 + P @ tmp ----
__global__ void mpost(const float* __restrict__ P, const float* __restrict__ tmp,
                      const float* __restrict__ m0p, float* __restrict__ out1){
  int w = threadIdx.x >> 6, l = threadIdx.x & 63;
  int m = blockIdx.x * 4 + w;
  if (m >= NM) return;
  float s = 0.f;
  #pragma unroll
  for (int i = 0; i < 9; ++i){
    int n = i * 64 + l;
    s += P[(size_t)m * NDP + n] * tmp[n];
  }
  #pragma unroll
  for (int off = 32; off; off >>= 1) s += __shfl_down(s, off);
  if (l == 0) out1[m] = m0p[0] + s;
}

extern "C" void kernel_launch(void* const* d_in, const int* in_sizes, int n_in,
                              void* d_out, int out_size, void* d_ws, size_t ws_size,
                              hipStream_t stream){
  const float* dist = (const float*)d_in[0];
  const float* F    = (const float*)d_in[1];
  const float* dobs = (const float*)d_in[2];
  const float* dcov = (const float*)d_in[3];
  const float* m0p  = (const float*)d_in[4];
  const float* lsp  = (const float*)d_in[5];
  const float* sgp  = (const float*)d_in[6];
  float* out = (float*)d_out;
  char* ws = (char*)d_ws;

  unsigned short* Bt = (unsigned short*)(ws + 0);
  float*          P  = (float*)(ws + 11538432);
  unsigned short* Pb = (unsigned short*)(ws + 34578432);
  float*          A  = (float*)(ws + 46116864);
  float*          r  = (float*)(ws + 47443968);
  float*          tp = (float*)(ws + 47446272);

  hipMemsetAsync(P, 0, (size_t)NM * NDP * sizeof(float), stream);
  prep_bt<<<NKB * 9, 256, 0, stream>>>(F, Bt);
  rvec<<<NDP, 256, 0, stream>>>(F, dobs, m0p, r);
  gemm1<<<MT1 * SPLITK, 512, 0, stream>>>(dist, Bt, P, lsp, sgp);
  conv_p<<<NKB * 9, 256, 0, stream>>>(P, Pb);
  a_init<<<(NDP * NDP) / 256, 256, 0, stream>>>(dcov, A);
  gemm2<<<81 * 3, 256, 0, stream>>>(Bt, Pb, A);
  for (int k = 0; k < 9; ++k){
    lu_diag<<<1, 256, 0, stream>>>(A, k * 64);
    if (k < 8){
      int nch = 8 - k;
      lu_trsm<<<2 * nch, 256, 0, stream>>>(A, k * 64);
      int nb = (NDP - k * 64 - 64) >> 5;
      lu_gemmk<<<nb * nb, 256, 0, stream>>>(A, k * 64);
    }
  }
  solve_ll<<<1, 576, 0, stream>>>(A, r, tp, out);
  mpost<<<2500, 256, 0, stream>>>(P, tp, m0p, out + 1);
}